// Round 11
// baseline (669.577 us; speedup 1.0000x reference)
//
#include <hip/hip_runtime.h>
#include <hip/hip_fp16.h>
#include <hip/hip_cooperative_groups.h>
#include <math.h>

namespace cg = cooperative_groups;

#define T 8
#define N 20000
#define E 320000
#define EPS 1e-5f
#define NBA 32         // agg-item sort blocks per t
#define CHUNKA 10000   // E/32 items per block
#define NPACK 10000    // wsum half-N tile
#define NPACK4 5000    // N/4 packed u32 (4 x u8 counters)
#define TILES_PT 1250  // 16-node MFMA tiles per t
#define BW 625         // nodes per dst-bucket
#define NBUK 32        // dst-buckets per t
#define SPAN_MAX 13824 // LDS stage cap (mean span 10000, sigma ~100)

typedef _Float16 f16x8 __attribute__((ext_vector_type(8)));
typedef float f32x4 __attribute__((ext_vector_type(4)));
struct h2x2 { __half2 lo, hi; };   // 8 B = 4 halfs

__device__ __forceinline__ float sigm(float x) { return 1.0f / (1.0f + expf(-x)); }

struct P {
    const float *x; const int *edges;
    const float *W1,*b1,*g1,*be1,*m1,*v1,*W2,*b2,*g2,*be2,*m2,*v2;
    const float *Wih0,*Whh0,*bih0,*bhh0,*Wih1,*Whh1,*bih1,*bhh1,*Wc,*bc;
    unsigned int *hist_g,*bpart; int *bcnt,*dega; float *dinv;
    int *offs,*eidx; float *wpart,*alpha; __half *xh,*vh,*W1t;
    float *pooled,*gx0_g; __half *Whh0h,*Whh1h,*Wih1h; float *out;
};

union SmemU {
    struct { unsigned int arr[CHUNKA]; int cnt[NBUK]; int cur[NBUK]; } a;   // partA 40.3 KB
    struct { int sbuf[SPAN_MAX]; int cursor[BW]; int offb[NBUK]; int lenb[NBUK]; } d; // 56.7 KB
    struct { int sh[1024]; } c;                                             // scanN
    struct { float pm[128]; float es[128]; } g8;                            // emb
    struct { float gx[T][512]; float ys[T][128]; float h[128]; float part[1024]; } h8; // head2 24.5 KB
};

// ONE cooperative kernel: 256 blocks x 1024 threads (1 block/CU), 8 phases
// split by grid.sync(). Eliminates ~7 dispatch gaps (~7 us each measured in
// R7) plus per-launch overhead. __launch_bounds__(1024,4) caps VGPR at 128
// (4 waves/SIMD) so 256 blocks are guaranteed co-resident.
__global__ __launch_bounds__(1024, 4) void k_all(P p) {
    cg::grid_group grid = cg::this_grid();
    __shared__ SmemU sm;
    const int bid = blockIdx.x;
    const int tid = threadIdx.x;

    // ---- Phase A: partition (merged u8 hist + bucket binning) -------------
    {
        const int t = bid & 7, b = bid >> 3;
        const int* keys = p.edges + (size_t)t * 2 * E + E + b * CHUNKA;  // dst
        const int* pays = p.edges + (size_t)t * 2 * E + b * CHUNKA;      // src
        for (int i = tid; i < NPACK4; i += 1024) sm.a.arr[i] = 0;
        if (tid < NBUK) sm.a.cnt[tid] = 0;
        __syncthreads();
        for (int i = tid; i < CHUNKA; i += 1024) {
            int k = keys[i];
            atomicAdd(&sm.a.arr[k >> 2], 1u << ((k & 3) * 8));
            atomicAdd(&sm.a.cnt[k / BW], 1);
        }
        __syncthreads();
        unsigned int* hout = p.hist_g + (size_t)(t * NBA + b) * NPACK4;
        for (int i = tid; i < NPACK4; i += 1024) hout[i] = sm.a.arr[i];
        if (tid == 0) {
            int run = 0;
            for (int u = 0; u < NBUK; u++) { sm.a.cur[u] = run; run += sm.a.cnt[u]; }
        }
        if (tid < NBUK) p.bcnt[(t * NBUK + tid) * NBUK + b] = sm.a.cnt[tid];
        __syncthreads();
        for (int i = tid; i < CHUNKA; i += 1024) {
            int k = keys[i];
            int pp = pays[i];
            int slot = atomicAdd(&sm.a.cur[k / BW], 1);
            sm.a.arr[slot] = ((unsigned int)k << 15) | (unsigned int)pp;
        }
        __syncthreads();
        unsigned int* outp = p.bpart + (size_t)(t * NBUK + b) * CHUNKA;
        for (int i = tid; i < CHUNKA; i += 1024) outp[i] = sm.a.arr[i];
    }
    grid.sync();

    // ---- Phase B: colsum (dega/dinv) + W1 transpose + pooled zero ---------
    {
        int g = bid * 1024 + tid;
        if (g < T * NPACK4) {
            int t = g / NPACK4, i = g - t * NPACK4;
            const unsigned int* hp = p.hist_g + (size_t)t * NBA * NPACK4 + i;
            unsigned int a0 = 0, a1 = 0, a2 = 0, a3 = 0;
#pragma unroll
            for (int b = 0; b < NBA; b++) {
                unsigned int h = hp[(size_t)b * NPACK4];
                a0 += h & 0xffu; a1 += (h >> 8) & 0xffu;
                a2 += (h >> 16) & 0xffu; a3 += h >> 24;
            }
            int4 dd; dd.x = (int)a0; dd.y = (int)a1; dd.z = (int)a2; dd.w = (int)a3;
            ((int4*)p.dega)[g] = dd;
            float4 df;
            df.x = rsqrtf((float)a0 + 1.0f); df.y = rsqrtf((float)a1 + 1.0f);
            df.z = rsqrtf((float)a2 + 1.0f); df.w = rsqrtf((float)a3 + 1.0f);
            ((float4*)p.dinv)[g] = df;
        } else if (g < T * NPACK4 + 8192) {
            int i = g - T * NPACK4;
            int j = i & 127, k = i >> 7;
            p.W1t[j * 64 + k] = __float2half(p.W1[i]);
        } else if (g < T * NPACK4 + 8192 + 256) {
            f32x4 z = {0.f, 0.f, 0.f, 0.f};
            ((f32x4*)p.pooled)[g - T * NPACK4 - 8192] = z;
        }
    }
    grid.sync();

    // ---- Phase C: scanN (blocks 0..7)  ||  cvt x->fp16 (blocks 8..255) ----
    if (bid < T) {
        const int t = bid;
        int local[20];
        int sum = 0;
        if (tid < 1000) {
            const int* tp = p.dega + t * N + tid * 20;
#pragma unroll
            for (int i = 0; i < 20; i++) { local[i] = tp[i]; sum += local[i]; }
        }
        sm.c.sh[tid] = sum;
        __syncthreads();
        for (int off = 1; off < 1024; off <<= 1) {
            int v = (tid >= off) ? sm.c.sh[tid - off] : 0;
            __syncthreads();
            sm.c.sh[tid] += v;
            __syncthreads();
        }
        if (tid < 1000) {
            int run = t * E + sm.c.sh[tid] - sum;
            int* op = p.offs + t * N + tid * 20;
#pragma unroll
            for (int i = 0; i < 20; i++) { op[i] = run; run += local[i]; }
        }
        if (t == T - 1 && tid == 0) p.offs[T * N] = T * E;
    } else {
        for (int idx = (bid - T) * 1024 + tid; idx < T * N * 16; idx += (256 - T) * 1024) {
            if (idx < 16) {                  // zero row for gather pad
                ushort4 z; z.x = 0; z.y = 0; z.z = 0; z.w = 0;
                ((ushort4*)(p.xh + (size_t)T * N * 64))[idx] = z;
            }
            float d = p.dinv[idx >> 4];
            f32x4 vv = __builtin_nontemporal_load((const f32x4*)p.x + idx);
            __half h0 = __float2half(vv.x * d);
            __half h1 = __float2half(vv.y * d);
            __half h2 = __float2half(vv.z * d);
            __half h3 = __float2half(vv.w * d);
            ushort4 pack;
            pack.x = *(unsigned short*)&h0;
            pack.y = *(unsigned short*)&h1;
            pack.z = *(unsigned short*)&h2;
            pack.w = *(unsigned short*)&h3;
            ((ushort4*)p.xh)[idx] = pack;
        }
    }
    grid.sync();

    // ---- Phase D: place (eidx) then wsum (wpart), per block ---------------
    {
        const int t = bid & 7, u = bid >> 3;
        const int nodeBase = t * N + u * BW;
        const int dstBase = u * BW;
        const int segStart = p.offs[nodeBase];
        const int segEnd = p.offs[nodeBase + BW];
        const int span = segEnd - segStart;
        if (tid < NBUK) {
            int s = 0;
            for (int uu = 0; uu < u; uu++) s += p.bcnt[(t * NBUK + uu) * NBUK + tid];
            sm.d.offb[tid] = s;
            sm.d.lenb[tid] = p.bcnt[(t * NBUK + u) * NBUK + tid];
        }
        for (int j = tid; j < BW; j += 1024) sm.d.cursor[j] = p.offs[nodeBase + j] - segStart;
        __syncthreads();
        if (span <= SPAN_MAX) {
            for (int b = 0; b < NBUK; b++) {
                const unsigned int* src = p.bpart + (size_t)(t * NBUK + b) * CHUNKA + sm.d.offb[b];
                int len = sm.d.lenb[b];
                for (int i = tid; i < len; i += 1024) {
                    unsigned int it = src[i];
                    int pos = atomicAdd(&sm.d.cursor[(int)(it >> 15) - dstBase], 1);
                    sm.d.sbuf[pos] = (int)(it & 0x7fffu) << 4;   // h2x2 units
                }
                __syncthreads();
            }
            int* out = p.eidx + segStart;
            for (int i = tid; i < span; i += 1024) out[i] = sm.d.sbuf[i];
        } else {                              // statistically unreachable fallback
            for (int b = 0; b < NBUK; b++) {
                const unsigned int* src = p.bpart + (size_t)(t * NBUK + b) * CHUNKA + sm.d.offb[b];
                int len = sm.d.lenb[b];
                for (int i = tid; i < len; i += 1024) {
                    unsigned int it = src[i];
                    int pos = atomicAdd(&sm.d.cursor[(int)(it >> 15) - dstBase], 1);
                    p.eidx[segStart + pos] = (int)(it & 0x7fffu) << 4;
                }
                __syncthreads();
            }
        }
        __syncthreads();
        // wsum for chunk (t, u), reusing sbuf as wf
        float* wf = (float*)sm.d.sbuf;
        const unsigned int* run = p.bpart + (size_t)(t * NBUK + u) * CHUNKA;
        const float* dv = p.dinv + t * N;
        for (int half = 0; half < 2; half++) {
            for (int i = tid; i < NPACK; i += 1024) wf[i] = 0.f;
            __syncthreads();
            int lo = half * NPACK;
            for (int i = tid; i < CHUNKA; i += 1024) {
                unsigned int it = run[i];
                int q = (int)(it & 0x7fffu) - lo;
                if (q >= 0 && q < NPACK) atomicAdd(&wf[q], dv[it >> 15]);
            }
            __syncthreads();
            float* out = p.wpart + (size_t)(t * NBUK + u) * N + lo;
            for (int i = tid; i < NPACK; i += 1024) out[i] = wf[i];
            __syncthreads();
        }
    }
    grid.sync();

    // ---- Phase E: wred (alpha) + gather (vh) ------------------------------
    {
        int g = bid * 1024 + tid;
        if (g < T * N) {
            int t = g / N, n = g - t * N;
            float s = 0.f;
#pragma unroll
            for (int b = 0; b < NBUK; b++) s += p.wpart[(size_t)(t * NBUK + b) * N + n];
            float di = p.dinv[g];
            p.alpha[g] = di * (s + di);
        }
    }
    {
        const int t = bid & 7;
        const int wv = tid >> 6, lane = tid & 63;
        const int wtid = (bid >> 3) * 16 + wv;     // 0..511 per t
        const int q = lane & 15, s = lane >> 4;
        const h2x2* xt4 = (const h2x2*)(p.xh + (size_t)t * N * 64);
        const int zrow = (T - t) * (N * 16);
        for (int n = wtid; n < N; n += 512) {
            const int node = t * N + n;
            const int st = p.offs[node];
            const int en = p.offs[node + 1];
            float a0 = 0.f, a1 = 0.f, a2 = 0.f, a3 = 0.f;
            for (int bs = st; bs < en; bs += 64) {
                int cnt = en - bs; if (cnt > 64) cnt = 64;
                int idx = zrow;
                if (lane < cnt) idx = __builtin_nontemporal_load(&p.eidx[bs + lane]);
                __half2 hlo = __float2half2_rn(0.f);
                __half2 hhi = __float2half2_rn(0.f);
                for (int e = 0; e < cnt; e += 16) {
                    int o0 = __shfl(idx, e + s),      o1 = __shfl(idx, e + 4 + s);
                    int o2 = __shfl(idx, e + 8 + s),  o3 = __shfl(idx, e + 12 + s);
                    h2x2 v0 = xt4[o0 + q], v1 = xt4[o1 + q];
                    h2x2 v2 = xt4[o2 + q], v3 = xt4[o3 + q];
                    __half2 p01l = __hadd2(v0.lo, v1.lo), p23l = __hadd2(v2.lo, v3.lo);
                    __half2 p01h = __hadd2(v0.hi, v1.hi), p23h = __hadd2(v2.hi, v3.hi);
                    hlo = __hadd2(hlo, __hadd2(p01l, p23l));
                    hhi = __hadd2(hhi, __hadd2(p01h, p23h));
                }
                float2 flo = __half22float2(hlo), fhi = __half22float2(hhi);
                a0 += flo.x; a1 += flo.y; a2 += fhi.x; a3 += fhi.y;
            }
            a0 += __shfl_xor(a0, 16); a1 += __shfl_xor(a1, 16);
            a2 += __shfl_xor(a2, 16); a3 += __shfl_xor(a3, 16);
            a0 += __shfl_xor(a0, 32); a1 += __shfl_xor(a1, 32);
            a2 += __shfl_xor(a2, 32); a3 += __shfl_xor(a3, 32);
            if (s == 0) {
                float di = p.dinv[node];
                h2x2 self = xt4[(n << 4) + q];
                float2 sl = __half22float2(self.lo), sh = __half22float2(self.hi);
                float r0 = di * (a0 + sl.x), r1 = di * (a1 + sl.y);
                float r2 = di * (a2 + sh.x), r3 = di * (a3 + sh.y);
                h2x2 outp;
                outp.lo = __floats2half2_rn(r0, r1);
                outp.hi = __floats2half2_rn(r2, r3);
                ((h2x2*)p.vh)[(size_t)node * 16 + q] = outp;
            }
        }
    }
    grid.sync();

    // ---- Phase F: MFMA layer-1 GEMM + BN/ReLU + alpha-pool ----------------
    {
        const int t = bid & 7;
        const int wv = tid >> 6, lane = tid & 63;
        const int wtid = (bid >> 3) * 16 + wv;     // 0..511 per t
        const int q4 = lane >> 4, col = lane & 15;
        const size_t tb = (size_t)t * N;
        f16x8 bfr[8][2];
        float sbv[8], stv[8];
#pragma unroll
        for (int jt = 0; jt < 8; jt++) {
            int j = jt * 16 + col;
            float sc = p.g1[j] * rsqrtf(p.v1[j] + EPS);
            sbv[jt] = sc;
            stv[jt] = sc * p.b1[j] + p.be1[j] - p.m1[j] * sc;
#pragma unroll
            for (int kk = 0; kk < 2; kk++)
                bfr[jt][kk] = *(const f16x8*)(p.W1t + (size_t)j * 64 + kk * 32 + q4 * 8);
        }
        float pool8[8];
#pragma unroll
        for (int jt = 0; jt < 8; jt++) pool8[jt] = 0.f;
        for (int tau = wtid; tau < TILES_PT; tau += 512) {
            int nb = tau * 16;
            const __half* vrow = p.vh + (tb + nb + col) * 64;
            f16x8 a0 = *(const f16x8*)(vrow + q4 * 8);
            f16x8 a1 = *(const f16x8*)(vrow + 32 + q4 * 8);
            float4 af = ((const float4*)(p.alpha + tb + nb))[q4];
#pragma unroll
            for (int jt = 0; jt < 8; jt++) {
                f32x4 acc = {0.f, 0.f, 0.f, 0.f};
                acc = __builtin_amdgcn_mfma_f32_16x16x32_f16(a0, bfr[jt][0], acc, 0, 0, 0);
                acc = __builtin_amdgcn_mfma_f32_16x16x32_f16(a1, bfr[jt][1], acc, 0, 0, 0);
                float sc = sbv[jt], sh = stv[jt];
                pool8[jt] += fmaxf(sc * acc[0] + sh, 0.f) * af.x
                           + fmaxf(sc * acc[1] + sh, 0.f) * af.y
                           + fmaxf(sc * acc[2] + sh, 0.f) * af.z
                           + fmaxf(sc * acc[3] + sh, 0.f) * af.w;
            }
        }
#pragma unroll
        for (int jt = 0; jt < 8; jt++) {
            pool8[jt] += __shfl_xor(pool8[jt], 16);
            pool8[jt] += __shfl_xor(pool8[jt], 32);
        }
        if (lane < 16) {
#pragma unroll
            for (int jt = 0; jt < 8; jt++)
                atomicAdd(&p.pooled[t * 128 + jt * 16 + lane], pool8[jt]);
        }
    }
    grid.sync();

    // ---- Phase G: emb/gx0 (blocks 0..7)  ||  fp16 weight convert (8..55) --
    if (bid < T) {
        const int t = bid;
        if (tid < 128) sm.g8.pm[tid] = p.pooled[t * 128 + tid] * (1.0f / N);
        __syncthreads();
        if (tid < 128) {
            float sc = p.g2[tid] * rsqrtf(p.v2[tid] + EPS);
            float sh = p.be2[tid] - p.m2[tid] * sc;
            float dot = 0.f;
#pragma unroll 8
            for (int k = 0; k < 128; k++) dot += sm.g8.pm[k] * p.W2[k * 128 + tid];
            sm.g8.es[tid] = sc * (dot + p.b2[tid]) + sh;
        }
        __syncthreads();
        if (tid < 512) {
            float dot = p.bih0[tid] + p.bhh0[tid];
            const float4* w = (const float4*)(p.Wih0 + tid * 128);
            const float4* e4 = (const float4*)sm.g8.es;
#pragma unroll
            for (int k4 = 0; k4 < 32; k4++) {
                float4 a = w[k4], bb = e4[k4];
                dot += a.x * bb.x + a.y * bb.y + a.z * bb.z + a.w * bb.w;
            }
            p.gx0_g[t * 512 + tid] = dot;
        }
    } else if (bid < T + 48) {
        int wb = bid - T;
        const float* src; __half* dst;
        if (wb < 16)      { src = p.Whh0; dst = p.Whh0h; }
        else if (wb < 32) { src = p.Whh1; dst = p.Whh1h; wb -= 16; }
        else              { src = p.Wih1; dst = p.Wih1h; wb -= 32; }
        int off = wb * 4096;
        for (int i = off + tid; i < off + 4096; i += 1024)
            dst[i] = __float2half(src[i]);
    }
    grid.sync();

    // ---- Phase H: serial LSTM head (block 0 only) -------------------------
    if (bid == 0) {
        const int r = tid & 511, hf = tid >> 9;
        float c = 0.f;
        for (int i = tid; i < T * 512; i += 1024) sm.h8.gx[i >> 9][i & 511] = p.gx0_g[i];
        if (tid < 128) sm.h8.h[tid] = 0.f;
        __syncthreads();
        // LSTM layer 0 (Whh0 fp16-streamed)
        {
            const h2x2* wrow = (const h2x2*)(p.Whh0h + r * 128 + hf * 64);
            for (int t = 0; t < T; t++) {
                const float4* h4 = ((const float4*)sm.h8.h) + hf * 16;
                float dot = 0.f;
#pragma unroll
                for (int k = 0; k < 16; k++) {
                    h2x2 wv = wrow[k];
                    float4 hv = h4[k];
                    float2 wl = __half22float2(wv.lo), wh = __half22float2(wv.hi);
                    dot += wl.x * hv.x + wl.y * hv.y + wh.x * hv.z + wh.y * hv.w;
                }
                sm.h8.part[tid] = dot;
                __syncthreads();
                if (tid < 128) {
                    float i_ = sm.h8.gx[t][tid]       + sm.h8.part[tid]       + sm.h8.part[512 + tid];
                    float f_ = sm.h8.gx[t][128 + tid] + sm.h8.part[128 + tid] + sm.h8.part[640 + tid];
                    float g_ = sm.h8.gx[t][256 + tid] + sm.h8.part[256 + tid] + sm.h8.part[768 + tid];
                    float o_ = sm.h8.gx[t][384 + tid] + sm.h8.part[384 + tid] + sm.h8.part[896 + tid];
                    c = sigm(f_) * c + sigm(i_) * tanhf(g_);
                    float hv = sigm(o_) * tanhf(c);
                    sm.h8.h[tid] = hv;
                    sm.h8.ys[t][tid] = hv;
                }
                __syncthreads();
            }
        }
        // gx1 = Wih1·ys + bias (fp16-streamed, overwrites gx)
        {
            const h2x2* wrow = (const h2x2*)(p.Wih1h + r * 128 + hf * 64);
            float bias = (hf == 0) ? (p.bih1[r] + p.bhh1[r]) : 0.f;
            for (int t = 0; t < T; t++) {
                const float4* y4 = ((const float4*)sm.h8.ys[t]) + hf * 16;
                float dot = bias;
#pragma unroll
                for (int k = 0; k < 16; k++) {
                    h2x2 wv = wrow[k];
                    float4 yv = y4[k];
                    float2 wl = __half22float2(wv.lo), wh = __half22float2(wv.hi);
                    dot += wl.x * yv.x + wl.y * yv.y + wh.x * yv.z + wh.y * yv.w;
                }
                sm.h8.part[tid] = dot;
                __syncthreads();
                if (tid < 512) sm.h8.gx[t][tid] = sm.h8.part[tid] + sm.h8.part[512 + tid];
                __syncthreads();
            }
        }
        // LSTM layer 1 (Whh1 fp16-streamed)
        if (tid < 128) sm.h8.h[tid] = 0.f;
        c = 0.f;
        __syncthreads();
        {
            const h2x2* wrow = (const h2x2*)(p.Whh1h + r * 128 + hf * 64);
            for (int t = 0; t < T; t++) {
                const float4* h4 = ((const float4*)sm.h8.h) + hf * 16;
                float dot = 0.f;
#pragma unroll
                for (int k = 0; k < 16; k++) {
                    h2x2 wv = wrow[k];
                    float4 hv = h4[k];
                    float2 wl = __half22float2(wv.lo), wh = __half22float2(wv.hi);
                    dot += wl.x * hv.x + wl.y * hv.y + wh.x * hv.z + wh.y * hv.w;
                }
                sm.h8.part[tid] = dot;
                __syncthreads();
                if (tid < 128) {
                    float i_ = sm.h8.gx[t][tid]       + sm.h8.part[tid]       + sm.h8.part[512 + tid];
                    float f_ = sm.h8.gx[t][128 + tid] + sm.h8.part[128 + tid] + sm.h8.part[640 + tid];
                    float g_ = sm.h8.gx[t][256 + tid] + sm.h8.part[256 + tid] + sm.h8.part[768 + tid];
                    float o_ = sm.h8.gx[t][384 + tid] + sm.h8.part[384 + tid] + sm.h8.part[896 + tid];
                    c = sigm(f_) * c + sigm(i_) * tanhf(g_);
                    sm.h8.h[tid] = sigm(o_) * tanhf(c);
                }
                __syncthreads();
            }
        }
        if (tid < 2) {
            float dot = p.bc[tid];
#pragma unroll 8
            for (int k = 0; k < 128; k++) dot += sm.h8.h[k] * p.Wc[tid * 128 + k];
            p.out[tid] = dot;
        }
        if (tid < 128) p.out[2 + tid] = sm.h8.h[tid];
    }
}

// ---------------------------------------------------------------------------
extern "C" void kernel_launch(void* const* d_in, const int* in_sizes, int n_in,
                              void* d_out, int out_size, void* d_ws, size_t ws_size,
                              hipStream_t stream) {
    P prm;
    prm.x    = (const float*)d_in[0];
    prm.edges= (const int*)d_in[1];
    prm.W1   = (const float*)d_in[2];
    prm.b1   = (const float*)d_in[3];
    prm.g1   = (const float*)d_in[4];
    prm.be1  = (const float*)d_in[5];
    prm.m1   = (const float*)d_in[6];
    prm.v1   = (const float*)d_in[7];
    prm.W2   = (const float*)d_in[8];
    prm.b2   = (const float*)d_in[9];
    prm.g2   = (const float*)d_in[10];
    prm.be2  = (const float*)d_in[11];
    prm.m2   = (const float*)d_in[12];
    prm.v2   = (const float*)d_in[13];
    prm.Wih0 = (const float*)d_in[14];
    prm.Whh0 = (const float*)d_in[15];
    prm.bih0 = (const float*)d_in[16];
    prm.bhh0 = (const float*)d_in[17];
    prm.Wih1 = (const float*)d_in[18];
    prm.Whh1 = (const float*)d_in[19];
    prm.bih1 = (const float*)d_in[20];
    prm.bhh1 = (const float*)d_in[21];
    prm.Wc   = (const float*)d_in[22];
    prm.bc   = (const float*)d_in[23];

    char* base = (char*)d_ws;
    // Aliasing: hist_g dead after Phase B; bpart dead after Phase D;
    // vh [0, 20.48 MB) written in Phase E.
    prm.hist_g = (unsigned int*)base;                          // T*NBA*NPACK4 u32
    prm.bpart  = (unsigned int*)(base + (size_t)T * NBA * NPACK * 4);
    prm.vh     = (__half*)base;                                // T*N*64 f16
    char* p = base + (size_t)T * NBA * NPACK * 4 + (size_t)T * NBUK * CHUNKA * 4;
    prm.xh    = (__half*)p;          p += (size_t)T * N * 64 * 2 + 128;  // + zero row
    prm.offs  = (int*)p;             p += (size_t)(T * N + 1) * 4 + 12;  // 16B align
    prm.dega  = (int*)p;             p += (size_t)T * N * 4;
    prm.dinv  = (float*)p;           p += (size_t)T * N * 4;
    prm.alpha = (float*)p;           p += (size_t)T * N * 4;
    prm.Whh0h = (__half*)p;          p += (size_t)65536 * 2;
    prm.Whh1h = (__half*)p;          p += (size_t)65536 * 2;
    prm.Wih1h = (__half*)p;          p += (size_t)65536 * 2;
    prm.gx0_g = (float*)p;           p += (size_t)T * 512 * 4;
    prm.eidx  = (int*)p;             p += (size_t)T * E * 4;             // 10.25 MB
    prm.wpart = (float*)p;           p += (size_t)T * NBUK * N * 4;      // 20.5 MB
    prm.bcnt  = (int*)p;             p += (size_t)T * NBUK * NBUK * 4;
    prm.pooled= (float*)p;           p += (size_t)T * 128 * 4;
    prm.W1t   = (__half*)p;
    prm.out   = (float*)d_out;

    void* kargs[] = { (void*)&prm };
    (void)hipLaunchCooperativeKernel((const void*)k_all, dim3(256), dim3(1024),
                                     kargs, 0, stream);
}

// Round 12
// 305.618 us; speedup vs baseline: 2.1909x; 2.1909x over previous
//
#include <hip/hip_runtime.h>
#include <hip/hip_fp16.h>
#include <math.h>

#define T 8
#define N 20000
#define E 320000
#define EPS 1e-5f
#define NBA 32         // agg-item sort blocks per t
#define CHUNKA 10000   // E/32 items per block
#define NPACK 10000    // u16-packed slot size / wsum half-N tile
#define NPACK4 5000    // N/4 packed u32 (4 x u8 counters)
#define TILES_PT 1250  // 16-node MFMA tiles per t
#define BW 625         // nodes per dst-bucket
#define NBUK 32        // dst-buckets per t
#define SPAN_MAX 13824 // LDS stage cap (mean span 10000, sigma ~100)
#define CSGRID 157     // ceil(T*NPACK4/256)
#define CVTBLK 2500    // ceil(T*N*16/1024) cvt blocks in k_pw
#define GBLK2 20000    // (T*N)/8 gather blocks (8 nodes per block, 2 per wave)
#define WREDBLK 625    // ceil(T*N/256) wred tail blocks in k_gather

typedef _Float16 f16x8 __attribute__((ext_vector_type(8)));
typedef float f32x4 __attribute__((ext_vector_type(4)));
struct h2x2 { __half2 lo, hi; };   // 8 B = 4 halfs

__device__ __forceinline__ float sigm(float x) { return 1.0f / (1.0f + expf(-x)); }

// ---------------------------------------------------------------------------
// K1: partition pass (merged hist). One read of the keys produces BOTH the
// per-node packed u8 histogram (-> hist_g for colsum) and per-bucket counts;
// a second read bins items (full dst<<15 | src) into LDS and writes the
// bucket-ordered run coalesced. Zero scattered global stores.
__global__ __launch_bounds__(1024) void k_partA(const int* __restrict__ edges,
                                                unsigned int* __restrict__ hist_g,
                                                unsigned int* __restrict__ bpart,
                                                int* __restrict__ bcnt) {
    __shared__ unsigned int arr[CHUNKA];   // 40 KB: hist (first 5000), then stage
    __shared__ int cnt[NBUK], cur[NBUK];
    const int t = blockIdx.x & 7, b = blockIdx.x >> 3;
    const int tid = threadIdx.x;
    const int* keys = edges + (size_t)t * 2 * E + E + b * CHUNKA;   // dst
    const int* pays = edges + (size_t)t * 2 * E + b * CHUNKA;       // src
    for (int i = tid; i < NPACK4; i += 1024) arr[i] = 0;
    if (tid < NBUK) cnt[tid] = 0;
    __syncthreads();
    for (int i = tid; i < CHUNKA; i += 1024) {
        int k = keys[i];
        atomicAdd(&arr[k >> 2], 1u << ((k & 3) * 8));   // u8 counters: per-node
        atomicAdd(&cnt[k / BW], 1);                     // per-chunk count <= ~50
    }
    __syncthreads();
    unsigned int* hout = hist_g + (size_t)(t * NBA + b) * NPACK4;
    for (int i = tid; i < NPACK4; i += 1024) hout[i] = arr[i];
    if (tid == 0) {
        int run = 0;
        for (int u = 0; u < NBUK; u++) { cur[u] = run; run += cnt[u]; }
    }
    if (tid < NBUK) bcnt[(t * NBUK + tid) * NBUK + b] = cnt[tid];
    __syncthreads();
    for (int i = tid; i < CHUNKA; i += 1024) {
        int k = keys[i];
        int p = pays[i];
        int slot = atomicAdd(&cur[k / BW], 1);
        arr[slot] = ((unsigned int)k << 15) | (unsigned int)p;
    }
    __syncthreads();
    unsigned int* outp = bpart + (size_t)(t * NBUK + b) * CHUNKA;
    for (int i = tid; i < CHUNKA; i += 1024) outp[i] = arr[i];
}

// K2a: column sum over the 32 agg blocks — dega = in-degree; dinv. u8 lanes.
// Fused tails: blocks >= CSGRID do the W1 fp16 transpose (old k_prepw) and
// block CSGRID zeros `pooled` (old memset).
__global__ __launch_bounds__(256) void k_colsum(
    const unsigned int* __restrict__ hist_g,
    int* __restrict__ dega, float* __restrict__ dinv,
    const float* __restrict__ W1, __half* __restrict__ W1t,
    float* __restrict__ pooled) {
    const int bid = blockIdx.x, tid = threadIdx.x;
    if (bid >= CSGRID) {                       // prepw + pooled-zero branch
        int i = (bid - CSGRID) * 256 + tid;    // 0..8191
        int j = i & 127, k = i >> 7;
        W1t[j * 64 + k] = __float2half(W1[i]);
        if (bid == CSGRID) {
            f32x4 z = {0.f, 0.f, 0.f, 0.f};
            ((f32x4*)pooled)[tid] = z;         // 256 x float4 = 1024 floats
        }
        return;
    }
    int idx = bid * 256 + tid;
    if (idx >= T * NPACK4) return;
    int t = idx / NPACK4, i = idx - t * NPACK4;
    const unsigned int* hp = hist_g + (size_t)t * NBA * NPACK4 + i;
    unsigned int a0 = 0, a1 = 0, a2 = 0, a3 = 0;
#pragma unroll
    for (int b = 0; b < NBA; b++) {
        unsigned int h = hp[(size_t)b * NPACK4];
        a0 += h & 0xffu; a1 += (h >> 8) & 0xffu;
        a2 += (h >> 16) & 0xffu; a3 += h >> 24;
    }
    int4 dd; dd.x = (int)a0; dd.y = (int)a1; dd.z = (int)a2; dd.w = (int)a3;
    ((int4*)dega)[idx] = dd;                      // 4*idx == t*N + 4*i
    float4 df;
    df.x = rsqrtf((float)a0 + 1.0f); df.y = rsqrtf((float)a1 + 1.0f);
    df.z = rsqrtf((float)a2 + 1.0f); df.w = rsqrtf((float)a3 + 1.0f);
    ((float4*)dinv)[idx] = df;
}

// K2b: per-t exclusive prefix over node in-degrees -> offs (+ sentinel).
__global__ __launch_bounds__(1024) void k_scanN(const int* __restrict__ dega,
                                                int* __restrict__ offs) {
    const int t = blockIdx.x, tid = threadIdx.x;
    __shared__ int sh[1024];
    int local[20];
    int sum = 0;
    if (tid < 1000) {
        const int* tp = dega + t * N + tid * 20;
#pragma unroll
        for (int i = 0; i < 20; i++) { local[i] = tp[i]; sum += local[i]; }
    }
    sh[tid] = sum;
    __syncthreads();
    for (int off = 1; off < 1024; off <<= 1) {
        int v = (tid >= off) ? sh[tid - off] : 0;
        __syncthreads();
        sh[tid] += v;
        __syncthreads();
    }
    if (tid < 1000) {
        int run = t * E + sh[tid] - sum;
        int* op = offs + t * N + tid * 20;
#pragma unroll
        for (int i = 0; i < 20; i++) { op[i] = run; run += local[i]; }
    }
    if (t == T - 1 && tid == 0) offs[T * N] = T * E;
}

// K3: MERGED place + wsum + cvt. Block-range branches; place & wsum are
// independent readers of bpart and overlap on-CU. cvt only needs dinv.
// eidx payload: src*16 (h2x2-unit row offset for the quad gather).
__global__ __launch_bounds__(1024) void k_pw(const unsigned int* __restrict__ bpart,
                                             const int* __restrict__ bcnt,
                                             const int* __restrict__ offs,
                                             const float* __restrict__ dinv,
                                             int* __restrict__ eidx,
                                             float* __restrict__ wpart,
                                             const float* __restrict__ x,
                                             __half* __restrict__ xh) {
    __shared__ int sbuf[SPAN_MAX];           // 54 KB (place: stage; wsum: wf)
    __shared__ int cursor[BW];
    __shared__ int offb[NBUK], lenb[NBUK];
    const int bid = blockIdx.x;
    const int tid = threadIdx.x;
    if (bid >= 2 * T * NBUK) {               // ---- cvt branch ----
        int idx = (bid - 2 * T * NBUK) * 1024 + tid;   // one f32x4 per thread
        if (idx >= T * N * 16) return;
        if (idx < 16) {                      // zero row for k_gather pad
            ushort4 z; z.x = 0; z.y = 0; z.z = 0; z.w = 0;
            ((ushort4*)(xh + (size_t)T * N * 64))[idx] = z;
        }
        float d = dinv[idx >> 4];
        f32x4 vv = __builtin_nontemporal_load((const f32x4*)x + idx);
        __half h0 = __float2half(vv.x * d);
        __half h1 = __float2half(vv.y * d);
        __half h2 = __float2half(vv.z * d);
        __half h3 = __float2half(vv.w * d);
        ushort4 pack;
        pack.x = *(unsigned short*)&h0;
        pack.y = *(unsigned short*)&h1;
        pack.z = *(unsigned short*)&h2;
        pack.w = *(unsigned short*)&h3;
        ((ushort4*)xh)[idx] = pack;
        return;
    }
    if (bid >= T * NBUK) {                   // ---- wsum branch ----
        float* wf = (float*)sbuf;            // first NPACK floats
        const int bb = bid - T * NBUK;
        const int t = bb & 7, b = bb >> 3;
        const unsigned int* run = bpart + (size_t)(t * NBUK + b) * CHUNKA;
        const float* dv = dinv + t * N;
        for (int half = 0; half < 2; half++) {
            for (int i = tid; i < NPACK; i += 1024) wf[i] = 0.f;
            __syncthreads();
            int lo = half * NPACK;
            for (int i = tid; i < CHUNKA; i += 1024) {
                unsigned int it = run[i];
                int q = (int)(it & 0x7fffu) - lo;
                if (q >= 0 && q < NPACK) atomicAdd(&wf[q], dv[it >> 15]);
            }
            __syncthreads();
            float* out = wpart + (size_t)(t * NBUK + b) * N + lo;
            for (int i = tid; i < NPACK; i += 1024) out[i] = wf[i];
            __syncthreads();
        }
        return;
    }
    // ---- place branch ----
    const int t = bid & 7, u = bid >> 3;
    const int nodeBase = t * N + u * BW;
    const int dstBase = u * BW;
    const int segStart = offs[nodeBase];
    const int segEnd = offs[nodeBase + BW];
    const int span = segEnd - segStart;
    if (tid < NBUK) {
        int s = 0;
        for (int uu = 0; uu < u; uu++) s += bcnt[(t * NBUK + uu) * NBUK + tid];
        offb[tid] = s;
        lenb[tid] = bcnt[(t * NBUK + u) * NBUK + tid];
    }
    for (int j = tid; j < BW; j += 1024) cursor[j] = offs[nodeBase + j] - segStart;
    __syncthreads();
    if (span <= SPAN_MAX) {
        for (int b = 0; b < NBUK; b++) {
            const unsigned int* src = bpart + (size_t)(t * NBUK + b) * CHUNKA + offb[b];
            int len = lenb[b];
            for (int i = tid; i < len; i += 1024) {
                unsigned int it = src[i];
                int pos = atomicAdd(&cursor[(int)(it >> 15) - dstBase], 1);
                sbuf[pos] = (int)(it & 0x7fffu) << 4;   // h2x2 units
            }
            __syncthreads();
        }
        int* out = eidx + segStart;
        for (int i = tid; i < span; i += 1024) out[i] = sbuf[i];
    } else {                                  // statistically unreachable fallback
        for (int b = 0; b < NBUK; b++) {
            const unsigned int* src = bpart + (size_t)(t * NBUK + b) * CHUNKA + offb[b];
            int len = lenb[b];
            for (int i = tid; i < len; i += 1024) {
                unsigned int it = src[i];
                int pos = atomicAdd(&cursor[(int)(it >> 15) - dstBase], 1);
                eidx[segStart + pos] = (int)(it & 0x7fffu) << 4;
            }
            __syncthreads();
        }
    }
}

// K4: gather — TWO nodes per wave (R12 ILP fix: R10's one-node chain had
// only 4 loads in flight and was latency-bound at 49% VALUBusy). Both eidx
// loads issue up-front; inner loop runs to max(cnt0,cnt1) with 8 xt4 loads
// in flight. Zero predication: lanes >= cnt hold zrow, so the shorter node
// accumulates exact fp16 zeros. Tail blocks (bid >= GBLK2) run wred.
__global__ __launch_bounds__(256) void k_gather(
    const int* __restrict__ eidx, const int* __restrict__ offs,
    const float* __restrict__ dinv, const __half* __restrict__ xh,
    const float* __restrict__ wpart, float* __restrict__ alpha,
    __half* __restrict__ vh) {
    const int bid = blockIdx.x;
    if (bid >= GBLK2) {                      // ---- wred tail ----
        int idx = (bid - GBLK2) * 256 + threadIdx.x;
        if (idx >= T * N) return;
        int t = idx / N, n = idx - t * N;
        float s = 0.f;
#pragma unroll
        for (int b = 0; b < NBUK; b++) s += wpart[(size_t)(t * NBUK + b) * N + n];
        float di = dinv[idx];
        alpha[idx] = di * (s + di);
        return;
    }
    const int t = bid & 7;
    const int n0 = ((bid >> 3) << 3) + ((threadIdx.x >> 6) << 1);  // pair base
    const int lane = threadIdx.x & 63;
    const int q = lane & 15, s = lane >> 4;
    const int node0 = t * N + n0;
    const int st0 = offs[node0];
    const int en0 = offs[node0 + 1];       // == st1
    const int en1 = offs[node0 + 2];
    const h2x2* xt4 = (const h2x2*)(xh + (size_t)t * N * 64);
    const int zrow = (T - t) * (N * 16);   // -> zeroed pad row, h2x2 units
    float a00 = 0.f, a01 = 0.f, a02 = 0.f, a03 = 0.f;
    float a10 = 0.f, a11 = 0.f, a12 = 0.f, a13 = 0.f;
    int bs0 = st0, bs1 = en0;
    const __half2 z2 = __float2half2_rn(0.f);
    while (bs0 < en0 || bs1 < en1) {
        int c0 = en0 - bs0; c0 = c0 < 0 ? 0 : (c0 > 64 ? 64 : c0);
        int c1 = en1 - bs1; c1 = c1 < 0 ? 0 : (c1 > 64 ? 64 : c1);
        int cm = c0 > c1 ? c0 : c1;
        int idx0 = zrow, idx1 = zrow;
        if (lane < c0) idx0 = __builtin_nontemporal_load(&eidx[bs0 + lane]);
        if (lane < c1) idx1 = __builtin_nontemporal_load(&eidx[bs1 + lane]);
        __half2 hlo0 = z2, hhi0 = z2, hlo1 = z2, hhi1 = z2;
        for (int e = 0; e < cm; e += 16) {
            int o00 = __shfl(idx0, e + s),      o01 = __shfl(idx0, e + 4 + s);
            int o02 = __shfl(idx0, e + 8 + s),  o03 = __shfl(idx0, e + 12 + s);
            int o10 = __shfl(idx1, e + s),      o11 = __shfl(idx1, e + 4 + s);
            int o12 = __shfl(idx1, e + 8 + s),  o13 = __shfl(idx1, e + 12 + s);
            h2x2 v00 = xt4[o00 + q], v01 = xt4[o01 + q];
            h2x2 v02 = xt4[o02 + q], v03 = xt4[o03 + q];
            h2x2 v10 = xt4[o10 + q], v11 = xt4[o11 + q];
            h2x2 v12 = xt4[o12 + q], v13 = xt4[o13 + q];
            __half2 p0l = __hadd2(__hadd2(v00.lo, v01.lo), __hadd2(v02.lo, v03.lo));
            __half2 p0h = __hadd2(__hadd2(v00.hi, v01.hi), __hadd2(v02.hi, v03.hi));
            __half2 p1l = __hadd2(__hadd2(v10.lo, v11.lo), __hadd2(v12.lo, v13.lo));
            __half2 p1h = __hadd2(__hadd2(v10.hi, v11.hi), __hadd2(v12.hi, v13.hi));
            hlo0 = __hadd2(hlo0, p0l); hhi0 = __hadd2(hhi0, p0h);
            hlo1 = __hadd2(hlo1, p1l); hhi1 = __hadd2(hhi1, p1h);
        }
        float2 fl0 = __half22float2(hlo0), fh0 = __half22float2(hhi0);
        float2 fl1 = __half22float2(hlo1), fh1 = __half22float2(hhi1);
        a00 += fl0.x; a01 += fl0.y; a02 += fh0.x; a03 += fh0.y;
        a10 += fl1.x; a11 += fl1.y; a12 += fh1.x; a13 += fh1.y;
        bs0 += 64; bs1 += 64;
    }
    // reduce over the 4 edge slots (lane bits 4,5)
    a00 += __shfl_xor(a00, 16); a01 += __shfl_xor(a01, 16);
    a02 += __shfl_xor(a02, 16); a03 += __shfl_xor(a03, 16);
    a10 += __shfl_xor(a10, 16); a11 += __shfl_xor(a11, 16);
    a12 += __shfl_xor(a12, 16); a13 += __shfl_xor(a13, 16);
    a00 += __shfl_xor(a00, 32); a01 += __shfl_xor(a01, 32);
    a02 += __shfl_xor(a02, 32); a03 += __shfl_xor(a03, 32);
    a10 += __shfl_xor(a10, 32); a11 += __shfl_xor(a11, 32);
    a12 += __shfl_xor(a12, 32); a13 += __shfl_xor(a13, 32);
    if (s == 0) {
        float di0 = dinv[node0];
        float di1 = dinv[node0 + 1];
        h2x2 self0 = xt4[(n0 << 4) + q];
        h2x2 self1 = xt4[((n0 + 1) << 4) + q];
        float2 s0l = __half22float2(self0.lo), s0h = __half22float2(self0.hi);
        float2 s1l = __half22float2(self1.lo), s1h = __half22float2(self1.hi);
        h2x2 out0, out1;
        out0.lo = __floats2half2_rn(di0 * (a00 + s0l.x), di0 * (a01 + s0l.y));
        out0.hi = __floats2half2_rn(di0 * (a02 + s0h.x), di0 * (a03 + s0h.y));
        out1.lo = __floats2half2_rn(di1 * (a10 + s1l.x), di1 * (a11 + s1l.y));
        out1.hi = __floats2half2_rn(di1 * (a12 + s1h.x), di1 * (a13 + s1h.y));
        ((h2x2*)vh)[(size_t)node0 * 16 + q] = out0;
        ((h2x2*)vh)[(size_t)(node0 + 1) * 16 + q] = out1;
    }
}

// K5: MFMA layer-1 GEMM (fp16 in, fp32 acc) + BN/ReLU + alpha-pool.
// alpha read as ONE float4 per tile (R7 shape; R9's inline-alpha regressed).
__global__ __launch_bounds__(256) void k_mfma_pool(
    const __half* __restrict__ vh, const float* __restrict__ alpha,
    const __half* __restrict__ W1t,
    const float* __restrict__ b1, const float* __restrict__ g1,
    const float* __restrict__ be1, const float* __restrict__ m1,
    const float* __restrict__ v1, float* __restrict__ pooled) {
    const int t = blockIdx.x & 7;
    const int bt = blockIdx.x >> 3;
    const int w = threadIdx.x >> 6, lane = threadIdx.x & 63;
    const int q = lane >> 4, col = lane & 15;
    const size_t tb = (size_t)t * N;

    f16x8 bfr[8][2];
    float sbv[8], stv[8];
#pragma unroll
    for (int jt = 0; jt < 8; jt++) {
        int j = jt * 16 + col;
        float s = g1[j] * rsqrtf(v1[j] + EPS);
        sbv[jt] = s;
        stv[jt] = s * b1[j] + be1[j] - m1[j] * s;
#pragma unroll
        for (int kk = 0; kk < 2; kk++)
            bfr[jt][kk] = *(const f16x8*)(W1t + (size_t)j * 64 + kk * 32 + q * 8);
    }
    float pool8[8];
#pragma unroll
    for (int jt = 0; jt < 8; jt++) pool8[jt] = 0.f;

    for (int i = 0; i < 8; i++) {
        int tau = bt * 32 + w * 8 + i;
        if (tau >= TILES_PT) break;
        int nb = tau * 16;
        const __half* vrow = vh + (tb + nb + col) * 64;
        f16x8 a0 = *(const f16x8*)(vrow + q * 8);
        f16x8 a1 = *(const f16x8*)(vrow + 32 + q * 8);
        float4 af = ((const float4*)(alpha + tb + nb))[q];
#pragma unroll
        for (int jt = 0; jt < 8; jt++) {
            f32x4 acc = {0.f, 0.f, 0.f, 0.f};
            acc = __builtin_amdgcn_mfma_f32_16x16x32_f16(a0, bfr[jt][0], acc, 0, 0, 0);
            acc = __builtin_amdgcn_mfma_f32_16x16x32_f16(a1, bfr[jt][1], acc, 0, 0, 0);
            float s = sbv[jt], sh = stv[jt];
            pool8[jt] += fmaxf(s * acc[0] + sh, 0.f) * af.x
                       + fmaxf(s * acc[1] + sh, 0.f) * af.y
                       + fmaxf(s * acc[2] + sh, 0.f) * af.z
                       + fmaxf(s * acc[3] + sh, 0.f) * af.w;
        }
    }
#pragma unroll
    for (int jt = 0; jt < 8; jt++) {
        pool8[jt] += __shfl_xor(pool8[jt], 16);
        pool8[jt] += __shfl_xor(pool8[jt], 32);
    }
    if (lane < 16) {
#pragma unroll
        for (int jt = 0; jt < 8; jt++)
            atomicAdd(&pooled[t * 128 + jt * 16 + lane], pool8[jt]);
    }
}

// K6: emb = bn2(pooled/N @ W2 + b2) + layer-0 x-part gates (8 parallel
// blocks, Wih0 STREAMED — no reg-cache, R17 spill trap). Blocks >= T
// (48 of them) convert Whh0/Whh1/Wih1 to fp16 — halves the bytes the
// serial k_head2 must stream through its one CU, and warms the caches.
__global__ __launch_bounds__(512) void k_emb(
    const float* __restrict__ pooled,
    const float* __restrict__ W2, const float* __restrict__ b2,
    const float* __restrict__ g2, const float* __restrict__ be2,
    const float* __restrict__ m2, const float* __restrict__ v2,
    const float* __restrict__ Wih0, const float* __restrict__ bih0,
    const float* __restrict__ bhh0, float* __restrict__ gx0_g,
    const float* __restrict__ Whh0, const float* __restrict__ Whh1,
    const float* __restrict__ Wih1,
    __half* __restrict__ Whh0h, __half* __restrict__ Whh1h,
    __half* __restrict__ Wih1h) {
    const int tid = threadIdx.x;
    if (blockIdx.x >= T) {                     // fp16-convert branch
        int wb = blockIdx.x - T;               // 0..47
        const float* src; __half* dst;
        if (wb < 16)      { src = Whh0; dst = Whh0h; }
        else if (wb < 32) { src = Whh1; dst = Whh1h; wb -= 16; }
        else              { src = Wih1; dst = Wih1h; wb -= 32; }
        int off = wb * 4096;                   // 65536/16 per block
        for (int i = off + tid; i < off + 4096; i += 512)
            dst[i] = __float2half(src[i]);
        return;
    }
    const int t = blockIdx.x;
    __shared__ float pm[128];
    __shared__ float es[128];
    if (tid < 128) pm[tid] = pooled[t * 128 + tid] * (1.0f / N);
    __syncthreads();
    if (tid < 128) {
        float s = g2[tid] * rsqrtf(v2[tid] + EPS);
        float sh = be2[tid] - m2[tid] * s;
        float dot = 0.f;
#pragma unroll 8
        for (int k = 0; k < 128; k++) dot += pm[k] * W2[k * 128 + tid];
        es[tid] = s * (dot + b2[tid]) + sh;
    }
    __syncthreads();
    float dot = bih0[tid] + bhh0[tid];
    const float4* w = (const float4*)(Wih0 + tid * 128);
    const float4* e4 = (const float4*)es;
#pragma unroll
    for (int k4 = 0; k4 < 32; k4++) {
        float4 a = w[k4], bb = e4[k4];
        dot += a.x * bb.x + a.y * bb.y + a.z * bb.z + a.w * bb.w;
    }
    gx0_g[t * 512 + tid] = dot;
}

// K7: serial head — lstm0 -> gx1 -> lstm1 -> classifier, single block.
// Weights STREAMED each step (reg-cache spills at 1024 thr) in FP16:
// per-step traffic 128 KB instead of 256 KB (R3's fp32 stream measured at
// the per-CU L2-BW ceiling, so bytes are the lever). absmax 3e-5 (R9).
__global__ __launch_bounds__(1024) void k_head2(
    const float* __restrict__ gx0_g,
    const __half* __restrict__ Whh0h, const __half* __restrict__ Wih1h,
    const __half* __restrict__ Whh1h,
    const float* __restrict__ bih1, const float* __restrict__ bhh1,
    const float* __restrict__ Wc, const float* __restrict__ bc,
    float* __restrict__ out) {
    __shared__ float gx[T][512];               // gx0, later overwritten by gx1
    __shared__ float ys[T][128];
    __shared__ float h[128];
    __shared__ float part[1024];
    const int tid = threadIdx.x;
    const int r = tid & 511, hf = tid >> 9;
    float c = 0.f;
    for (int i = tid; i < T * 512; i += 1024) gx[i >> 9][i & 511] = gx0_g[i];
    if (tid < 128) h[tid] = 0.f;
    __syncthreads();
    // ---- LSTM layer 0 (Whh0 fp16-streamed) ----
    {
        const h2x2* wrow = (const h2x2*)(Whh0h + r * 128 + hf * 64);
        for (int t = 0; t < T; t++) {
            const float4* h4 = ((const float4*)h) + hf * 16;
            float dot = 0.f;
#pragma unroll
            for (int k = 0; k < 16; k++) {
                h2x2 wv = wrow[k];
                float4 hv = h4[k];
                float2 wl = __half22float2(wv.lo), wh = __half22float2(wv.hi);
                dot += wl.x * hv.x + wl.y * hv.y + wh.x * hv.z + wh.y * hv.w;
            }
            part[tid] = dot;
            __syncthreads();
            if (tid < 128) {
                float i_ = gx[t][tid]       + part[tid]       + part[512 + tid];
                float f_ = gx[t][128 + tid] + part[128 + tid] + part[640 + tid];
                float g_ = gx[t][256 + tid] + part[256 + tid] + part[768 + tid];
                float o_ = gx[t][384 + tid] + part[384 + tid] + part[896 + tid];
                c = sigm(f_) * c + sigm(i_) * tanhf(g_);
                float hv = sigm(o_) * tanhf(c);
                h[tid] = hv;
                ys[t][tid] = hv;
            }
            __syncthreads();
        }
    }
    // ---- gx1[t][r] = Wih1[r]·ys[t] + bias (fp16-streamed, overwrites gx) ----
    {
        const h2x2* wrow = (const h2x2*)(Wih1h + r * 128 + hf * 64);
        float bias = (hf == 0) ? (bih1[r] + bhh1[r]) : 0.f;
        for (int t = 0; t < T; t++) {
            const float4* y4 = ((const float4*)ys[t]) + hf * 16;
            float dot = bias;
#pragma unroll
            for (int k = 0; k < 16; k++) {
                h2x2 wv = wrow[k];
                float4 yv = y4[k];
                float2 wl = __half22float2(wv.lo), wh = __half22float2(wv.hi);
                dot += wl.x * yv.x + wl.y * yv.y + wh.x * yv.z + wh.y * yv.w;
            }
            part[tid] = dot;
            __syncthreads();
            if (tid < 512) gx[t][tid] = part[tid] + part[512 + tid];
            __syncthreads();
        }
    }
    // ---- LSTM layer 1 (Whh1 fp16-streamed) ----
    if (tid < 128) h[tid] = 0.f;
    c = 0.f;
    __syncthreads();
    {
        const h2x2* wrow = (const h2x2*)(Whh1h + r * 128 + hf * 64);
        for (int t = 0; t < T; t++) {
            const float4* h4 = ((const float4*)h) + hf * 16;
            float dot = 0.f;
#pragma unroll
            for (int k = 0; k < 16; k++) {
                h2x2 wv = wrow[k];
                float4 hv = h4[k];
                float2 wl = __half22float2(wv.lo), wh = __half22float2(wv.hi);
                dot += wl.x * hv.x + wl.y * hv.y + wh.x * hv.z + wh.y * hv.w;
            }
            part[tid] = dot;
            __syncthreads();
            if (tid < 128) {
                float i_ = gx[t][tid]       + part[tid]       + part[512 + tid];
                float f_ = gx[t][128 + tid] + part[128 + tid] + part[640 + tid];
                float g_ = gx[t][256 + tid] + part[256 + tid] + part[768 + tid];
                float o_ = gx[t][384 + tid] + part[384 + tid] + part[896 + tid];
                c = sigm(f_) * c + sigm(i_) * tanhf(g_);
                h[tid] = sigm(o_) * tanhf(c);
            }
            __syncthreads();
        }
    }
    if (tid < 2) {
        float dot = bc[tid];
#pragma unroll 8
        for (int k = 0; k < 128; k++) dot += h[k] * Wc[tid * 128 + k];
        out[tid] = dot;
    }
    if (tid < 128) out[2 + tid] = h[tid];
}

// ---------------------------------------------------------------------------
extern "C" void kernel_launch(void* const* d_in, const int* in_sizes, int n_in,
                              void* d_out, int out_size, void* d_ws, size_t ws_size,
                              hipStream_t stream) {
    const float* x    = (const float*)d_in[0];
    const int*   edges= (const int*)d_in[1];
    const float* W1   = (const float*)d_in[2];
    const float* b1   = (const float*)d_in[3];
    const float* g1   = (const float*)d_in[4];
    const float* be1  = (const float*)d_in[5];
    const float* m1   = (const float*)d_in[6];
    const float* v1   = (const float*)d_in[7];
    const float* W2   = (const float*)d_in[8];
    const float* b2   = (const float*)d_in[9];
    const float* g2   = (const float*)d_in[10];
    const float* be2  = (const float*)d_in[11];
    const float* m2   = (const float*)d_in[12];
    const float* v2   = (const float*)d_in[13];
    const float* Wih0 = (const float*)d_in[14];
    const float* Whh0 = (const float*)d_in[15];
    const float* bih0 = (const float*)d_in[16];
    const float* bhh0 = (const float*)d_in[17];
    const float* Wih1 = (const float*)d_in[18];
    const float* Whh1 = (const float*)d_in[19];
    const float* bih1 = (const float*)d_in[20];
    const float* bhh1 = (const float*)d_in[21];
    const float* Wc   = (const float*)d_in[22];
    const float* bc   = (const float*)d_in[23];

    char* base = (char*)d_ws;
    // Aliasing: hist_g dead after k_colsum; bpart written in k_partA, read by
    // k_pw (place+wsum), then dead; vh [0, 20.48 MB) written in k_gather.
    unsigned int* hist_g = (unsigned int*)base;                       // T*NBA*NPACK4 u32
    unsigned int* bpart  = (unsigned int*)(base + (size_t)T * NBA * NPACK * 4);
    __half*       vh     = (__half*)base;                             // T*N*64 f16
    char* p = base + (size_t)T * NBA * NPACK * 4 + (size_t)T * NBUK * CHUNKA * 4;
    __half* xh    = (__half*)p;             p += (size_t)T * N * 64 * 2 + 128; // + zero row
    int*   offs   = (int*)p;                p += (size_t)(T * N + 1) * 4 + 12; // keep 16B align
    int*   dega   = (int*)p;                p += (size_t)T * N * 4;
    float* dinv   = (float*)p;              p += (size_t)T * N * 4;
    float* alpha  = (float*)p;              p += (size_t)T * N * 4;
    __half* Whh0h = (__half*)p;             p += (size_t)65536 * 2;   // fp16 weights
    __half* Whh1h = (__half*)p;             p += (size_t)65536 * 2;
    __half* Wih1h = (__half*)p;             p += (size_t)65536 * 2;
    float* gx0_g  = (float*)p;              p += (size_t)T * 512 * 4;
    int*   eidx   = (int*)p;                p += (size_t)T * E * 4;   // 10.25 MB
    float* wpart  = (float*)p;              p += (size_t)T * NBUK * N * 4; // 20.5 MB
    int*   bcnt   = (int*)p;                p += (size_t)T * NBUK * NBUK * 4;
    float* pooled = (float*)p;              p += (size_t)T * 128 * 4;
    __half* W1t   = (__half*)p;

    k_partA<<<T * NBUK, 1024, 0, stream>>>(edges, hist_g, bpart, bcnt);
    k_colsum<<<CSGRID + 32, 256, 0, stream>>>(hist_g, dega, dinv, W1, W1t, pooled);
    k_scanN<<<T, 1024, 0, stream>>>(dega, offs);
    k_pw<<<2 * T * NBUK + CVTBLK, 1024, 0, stream>>>(bpart, bcnt, offs, dinv,
                                                     eidx, wpart, x, xh);
    k_gather<<<GBLK2 + WREDBLK, 256, 0, stream>>>(eidx, offs, dinv, xh, wpart, alpha, vh);
    k_mfma_pool<<<8 * 40, 256, 0, stream>>>(vh, alpha, W1t, b1, g1, be1, m1, v1, pooled);
    k_emb<<<T + 48, 512, 0, stream>>>(pooled, W2, b2, g2, be2, m2, v2,
                                      Wih0, bih0, bhh0, gx0_g,
                                      Whh0, Whh1, Wih1, Whh0h, Whh1h, Wih1h);
    k_head2<<<1, 1024, 0, stream>>>(gx0_g, Whh0h, Wih1h, Whh1h,
                                    bih1, bhh1, Wc, bc, (float*)d_out);
}

// Round 13
// 305.165 us; speedup vs baseline: 2.1941x; 1.0015x over previous
//
#include <hip/hip_runtime.h>
#include <hip/hip_fp16.h>
#include <math.h>

#define T 8
#define N 20000
#define E 320000
#define EPS 1e-5f
#define NBA 32         // agg-item sort blocks per t
#define CHUNKA 10000   // E/32 items per block
#define NPACK 10000    // u16-packed slot size / wsum half-N tile
#define NPACK4 5000    // N/4 packed u32 (4 x u8 counters)
#define TILES_PT 1250  // 16-node MFMA tiles per t
#define BW 625         // nodes per dst-bucket
#define NBUK 32        // dst-buckets per t
#define SPAN_MAX 13824 // LDS stage cap (mean span 10000, sigma ~100)
#define CSGRID 157     // ceil(T*NPACK4/256)
#define CVTBLK 2500    // ceil(T*N*16/1024) cvt blocks in k_pw
#define GBLK2 20000    // (T*N)/8 gather blocks (8 nodes per block, 2 per wave)
#define WREDBLK 625    // ceil(T*N/256) wred tail blocks in k_gather

typedef _Float16 f16x8 __attribute__((ext_vector_type(8)));
typedef float f32x4 __attribute__((ext_vector_type(4)));
struct h2x2 { __half2 lo, hi; };   // 8 B = 4 halfs

__device__ __forceinline__ float sigm(float x) { return 1.0f / (1.0f + expf(-x)); }

// ---------------------------------------------------------------------------
// K1: partition pass (merged hist). One read of the keys produces BOTH the
// per-node packed u8 histogram (-> hist_g for colsum) and per-bucket counts;
// a second read bins items (full dst<<15 | src) into LDS and writes the
// bucket-ordered run coalesced. Zero scattered global stores.
// Tail blocks (bid >= T*NBA, 48 of them): fp16-convert the LSTM weights
// (moved here from k_emb — zero deps on pipeline state, runs for free
// alongside the heavy partition blocks; kernel-boundary ordering guarantees
// visibility to k_head2 seven dispatches later).
__global__ __launch_bounds__(1024) void k_partA(const int* __restrict__ edges,
                                                unsigned int* __restrict__ hist_g,
                                                unsigned int* __restrict__ bpart,
                                                int* __restrict__ bcnt,
                                                const float* __restrict__ Whh0,
                                                const float* __restrict__ Whh1,
                                                const float* __restrict__ Wih1,
                                                __half* __restrict__ Whh0h,
                                                __half* __restrict__ Whh1h,
                                                __half* __restrict__ Wih1h) {
    __shared__ unsigned int arr[CHUNKA];   // 40 KB: hist (first 5000), then stage
    __shared__ int cnt[NBUK], cur[NBUK];
    const int bidx = blockIdx.x;
    const int tid = threadIdx.x;
    if (bidx >= T * NBA) {                 // ---- fp16-convert tails ----
        int wb = bidx - T * NBA;           // 0..47
        const float* src; __half* dst;
        if (wb < 16)      { src = Whh0; dst = Whh0h; }
        else if (wb < 32) { src = Whh1; dst = Whh1h; wb -= 16; }
        else              { src = Wih1; dst = Wih1h; wb -= 32; }
        int off = wb * 4096;               // 65536/16 per block
        for (int i = off + tid; i < off + 4096; i += 1024)
            dst[i] = __float2half(src[i]);
        return;
    }
    const int t = bidx & 7, b = bidx >> 3;
    const int* keys = edges + (size_t)t * 2 * E + E + b * CHUNKA;   // dst
    const int* pays = edges + (size_t)t * 2 * E + b * CHUNKA;       // src
    for (int i = tid; i < NPACK4; i += 1024) arr[i] = 0;
    if (tid < NBUK) cnt[tid] = 0;
    __syncthreads();
    for (int i = tid; i < CHUNKA; i += 1024) {
        int k = keys[i];
        atomicAdd(&arr[k >> 2], 1u << ((k & 3) * 8));   // u8 counters: per-node
        atomicAdd(&cnt[k / BW], 1);                     // per-chunk count <= ~50
    }
    __syncthreads();
    unsigned int* hout = hist_g + (size_t)(t * NBA + b) * NPACK4;
    for (int i = tid; i < NPACK4; i += 1024) hout[i] = arr[i];
    if (tid == 0) {
        int run = 0;
        for (int u = 0; u < NBUK; u++) { cur[u] = run; run += cnt[u]; }
    }
    if (tid < NBUK) bcnt[(t * NBUK + tid) * NBUK + b] = cnt[tid];
    __syncthreads();
    for (int i = tid; i < CHUNKA; i += 1024) {
        int k = keys[i];
        int p = pays[i];
        int slot = atomicAdd(&cur[k / BW], 1);
        arr[slot] = ((unsigned int)k << 15) | (unsigned int)p;
    }
    __syncthreads();
    unsigned int* outp = bpart + (size_t)(t * NBUK + b) * CHUNKA;
    for (int i = tid; i < CHUNKA; i += 1024) outp[i] = arr[i];
}

// K2a: column sum over the 32 agg blocks — dega = in-degree; dinv. u8 lanes.
// Fused tails: blocks >= CSGRID do the W1 fp16 transpose (old k_prepw) and
// block CSGRID zeros `pooled` (old memset).
__global__ __launch_bounds__(256) void k_colsum(
    const unsigned int* __restrict__ hist_g,
    int* __restrict__ dega, float* __restrict__ dinv,
    const float* __restrict__ W1, __half* __restrict__ W1t,
    float* __restrict__ pooled) {
    const int bid = blockIdx.x, tid = threadIdx.x;
    if (bid >= CSGRID) {                       // prepw + pooled-zero branch
        int i = (bid - CSGRID) * 256 + tid;    // 0..8191
        int j = i & 127, k = i >> 7;
        W1t[j * 64 + k] = __float2half(W1[i]);
        if (bid == CSGRID) {
            f32x4 z = {0.f, 0.f, 0.f, 0.f};
            ((f32x4*)pooled)[tid] = z;         // 256 x float4 = 1024 floats
        }
        return;
    }
    int idx = bid * 256 + tid;
    if (idx >= T * NPACK4) return;
    int t = idx / NPACK4, i = idx - t * NPACK4;
    const unsigned int* hp = hist_g + (size_t)t * NBA * NPACK4 + i;
    unsigned int a0 = 0, a1 = 0, a2 = 0, a3 = 0;
#pragma unroll
    for (int b = 0; b < NBA; b++) {
        unsigned int h = hp[(size_t)b * NPACK4];
        a0 += h & 0xffu; a1 += (h >> 8) & 0xffu;
        a2 += (h >> 16) & 0xffu; a3 += h >> 24;
    }
    int4 dd; dd.x = (int)a0; dd.y = (int)a1; dd.z = (int)a2; dd.w = (int)a3;
    ((int4*)dega)[idx] = dd;                      // 4*idx == t*N + 4*i
    float4 df;
    df.x = rsqrtf((float)a0 + 1.0f); df.y = rsqrtf((float)a1 + 1.0f);
    df.z = rsqrtf((float)a2 + 1.0f); df.w = rsqrtf((float)a3 + 1.0f);
    ((float4*)dinv)[idx] = df;
}

// K2b: per-t exclusive prefix over node in-degrees -> offs (+ sentinel).
__global__ __launch_bounds__(1024) void k_scanN(const int* __restrict__ dega,
                                                int* __restrict__ offs) {
    const int t = blockIdx.x, tid = threadIdx.x;
    __shared__ int sh[1024];
    int local[20];
    int sum = 0;
    if (tid < 1000) {
        const int* tp = dega + t * N + tid * 20;
#pragma unroll
        for (int i = 0; i < 20; i++) { local[i] = tp[i]; sum += local[i]; }
    }
    sh[tid] = sum;
    __syncthreads();
    for (int off = 1; off < 1024; off <<= 1) {
        int v = (tid >= off) ? sh[tid - off] : 0;
        __syncthreads();
        sh[tid] += v;
        __syncthreads();
    }
    if (tid < 1000) {
        int run = t * E + sh[tid] - sum;
        int* op = offs + t * N + tid * 20;
#pragma unroll
        for (int i = 0; i < 20; i++) { op[i] = run; run += local[i]; }
    }
    if (t == T - 1 && tid == 0) offs[T * N] = T * E;
}

// K3: MERGED place + wsum + cvt. Block-range branches. R13: wsum split into
// 2x256 single-half blocks (was 256 blocks x 2 serial half-passes) — halves
// the wsum branch's critical path so pw's duration tracks place instead.
// eidx payload: src*16 (h2x2-unit row offset for the quad gather).
__global__ __launch_bounds__(1024) void k_pw(const unsigned int* __restrict__ bpart,
                                             const int* __restrict__ bcnt,
                                             const int* __restrict__ offs,
                                             const float* __restrict__ dinv,
                                             int* __restrict__ eidx,
                                             float* __restrict__ wpart,
                                             const float* __restrict__ x,
                                             __half* __restrict__ xh) {
    __shared__ int sbuf[SPAN_MAX];           // 54 KB (place: stage; wsum: wf)
    __shared__ int cursor[BW];
    __shared__ int offb[NBUK], lenb[NBUK];
    const int bid = blockIdx.x;
    const int tid = threadIdx.x;
    if (bid >= 3 * T * NBUK) {               // ---- cvt branch ----
        int idx = (bid - 3 * T * NBUK) * 1024 + tid;   // one f32x4 per thread
        if (idx >= T * N * 16) return;
        if (idx < 16) {                      // zero row for k_gather pad
            ushort4 z; z.x = 0; z.y = 0; z.z = 0; z.w = 0;
            ((ushort4*)(xh + (size_t)T * N * 64))[idx] = z;
        }
        float d = dinv[idx >> 4];
        f32x4 vv = __builtin_nontemporal_load((const f32x4*)x + idx);
        __half h0 = __float2half(vv.x * d);
        __half h1 = __float2half(vv.y * d);
        __half h2 = __float2half(vv.z * d);
        __half h3 = __float2half(vv.w * d);
        ushort4 pack;
        pack.x = *(unsigned short*)&h0;
        pack.y = *(unsigned short*)&h1;
        pack.z = *(unsigned short*)&h2;
        pack.w = *(unsigned short*)&h3;
        ((ushort4*)xh)[idx] = pack;
        return;
    }
    if (bid >= T * NBUK) {                   // ---- wsum branch (one half) ----
        float* wf = (float*)sbuf;            // first NPACK floats
        const int bb = bid - T * NBUK;       // 0..511
        const int half = bb >> 8;            // 0 or 1
        const int cb = bb & 255;
        const int t = cb & 7, b = cb >> 3;
        const unsigned int* run = bpart + (size_t)(t * NBUK + b) * CHUNKA;
        const float* dv = dinv + t * N;
        for (int i = tid; i < NPACK; i += 1024) wf[i] = 0.f;
        __syncthreads();
        int lo = half * NPACK;
        for (int i = tid; i < CHUNKA; i += 1024) {
            unsigned int it = run[i];
            int q = (int)(it & 0x7fffu) - lo;
            if (q >= 0 && q < NPACK) atomicAdd(&wf[q], dv[it >> 15]);
        }
        __syncthreads();
        float* out = wpart + (size_t)(t * NBUK + b) * N + lo;
        for (int i = tid; i < NPACK; i += 1024) out[i] = wf[i];
        return;
    }
    // ---- place branch ----
    const int t = bid & 7, u = bid >> 3;
    const int nodeBase = t * N + u * BW;
    const int dstBase = u * BW;
    const int segStart = offs[nodeBase];
    const int segEnd = offs[nodeBase + BW];
    const int span = segEnd - segStart;
    if (tid < NBUK) {
        int s = 0;
        for (int uu = 0; uu < u; uu++) s += bcnt[(t * NBUK + uu) * NBUK + tid];
        offb[tid] = s;
        lenb[tid] = bcnt[(t * NBUK + u) * NBUK + tid];
    }
    for (int j = tid; j < BW; j += 1024) cursor[j] = offs[nodeBase + j] - segStart;
    __syncthreads();
    if (span <= SPAN_MAX) {
        for (int b = 0; b < NBUK; b++) {
            const unsigned int* src = bpart + (size_t)(t * NBUK + b) * CHUNKA + offb[b];
            int len = lenb[b];
            for (int i = tid; i < len; i += 1024) {
                unsigned int it = src[i];
                int pos = atomicAdd(&cursor[(int)(it >> 15) - dstBase], 1);
                sbuf[pos] = (int)(it & 0x7fffu) << 4;   // h2x2 units
            }
            __syncthreads();
        }
        int* out = eidx + segStart;
        for (int i = tid; i < span; i += 1024) out[i] = sbuf[i];
    } else {                                  // statistically unreachable fallback
        for (int b = 0; b < NBUK; b++) {
            const unsigned int* src = bpart + (size_t)(t * NBUK + b) * CHUNKA + offb[b];
            int len = lenb[b];
            for (int i = tid; i < len; i += 1024) {
                unsigned int it = src[i];
                int pos = atomicAdd(&cursor[(int)(it >> 15) - dstBase], 1);
                eidx[segStart + pos] = (int)(it & 0x7fffu) << 4;
            }
            __syncthreads();
        }
    }
}

// K4: gather — TWO nodes per wave. Both eidx loads issue up-front; inner
// loop runs to max(cnt0,cnt1) with 8 xt4 loads in flight. Zero predication:
// lanes >= cnt hold zrow, so the shorter node accumulates exact fp16 zeros.
// Tail blocks (bid >= GBLK2) run wred. [R12 measured: ILP beyond this is
// not the limit — gather co-saturates LDS(bpermute)/VMEM/VALU pipes.]
__global__ __launch_bounds__(256) void k_gather(
    const int* __restrict__ eidx, const int* __restrict__ offs,
    const float* __restrict__ dinv, const __half* __restrict__ xh,
    const float* __restrict__ wpart, float* __restrict__ alpha,
    __half* __restrict__ vh) {
    const int bid = blockIdx.x;
    if (bid >= GBLK2) {                      // ---- wred tail ----
        int idx = (bid - GBLK2) * 256 + threadIdx.x;
        if (idx >= T * N) return;
        int t = idx / N, n = idx - t * N;
        float s = 0.f;
#pragma unroll
        for (int b = 0; b < NBUK; b++) s += wpart[(size_t)(t * NBUK + b) * N + n];
        float di = dinv[idx];
        alpha[idx] = di * (s + di);
        return;
    }
    const int t = bid & 7;
    const int n0 = ((bid >> 3) << 3) + ((threadIdx.x >> 6) << 1);  // pair base
    const int lane = threadIdx.x & 63;
    const int q = lane & 15, s = lane >> 4;
    const int node0 = t * N + n0;
    const int st0 = offs[node0];
    const int en0 = offs[node0 + 1];       // == st1
    const int en1 = offs[node0 + 2];
    const h2x2* xt4 = (const h2x2*)(xh + (size_t)t * N * 64);
    const int zrow = (T - t) * (N * 16);   // -> zeroed pad row, h2x2 units
    float a00 = 0.f, a01 = 0.f, a02 = 0.f, a03 = 0.f;
    float a10 = 0.f, a11 = 0.f, a12 = 0.f, a13 = 0.f;
    int bs0 = st0, bs1 = en0;
    const __half2 z2 = __float2half2_rn(0.f);
    while (bs0 < en0 || bs1 < en1) {
        int c0 = en0 - bs0; c0 = c0 < 0 ? 0 : (c0 > 64 ? 64 : c0);
        int c1 = en1 - bs1; c1 = c1 < 0 ? 0 : (c1 > 64 ? 64 : c1);
        int cm = c0 > c1 ? c0 : c1;
        int idx0 = zrow, idx1 = zrow;
        if (lane < c0) idx0 = __builtin_nontemporal_load(&eidx[bs0 + lane]);
        if (lane < c1) idx1 = __builtin_nontemporal_load(&eidx[bs1 + lane]);
        __half2 hlo0 = z2, hhi0 = z2, hlo1 = z2, hhi1 = z2;
        for (int e = 0; e < cm; e += 16) {
            int o00 = __shfl(idx0, e + s),      o01 = __shfl(idx0, e + 4 + s);
            int o02 = __shfl(idx0, e + 8 + s),  o03 = __shfl(idx0, e + 12 + s);
            int o10 = __shfl(idx1, e + s),      o11 = __shfl(idx1, e + 4 + s);
            int o12 = __shfl(idx1, e + 8 + s),  o13 = __shfl(idx1, e + 12 + s);
            h2x2 v00 = xt4[o00 + q], v01 = xt4[o01 + q];
            h2x2 v02 = xt4[o02 + q], v03 = xt4[o03 + q];
            h2x2 v10 = xt4[o10 + q], v11 = xt4[o11 + q];
            h2x2 v12 = xt4[o12 + q], v13 = xt4[o13 + q];
            __half2 p0l = __hadd2(__hadd2(v00.lo, v01.lo), __hadd2(v02.lo, v03.lo));
            __half2 p0h = __hadd2(__hadd2(v00.hi, v01.hi), __hadd2(v02.hi, v03.hi));
            __half2 p1l = __hadd2(__hadd2(v10.lo, v11.lo), __hadd2(v12.lo, v13.lo));
            __half2 p1h = __hadd2(__hadd2(v10.hi, v11.hi), __hadd2(v12.hi, v13.hi));
            hlo0 = __hadd2(hlo0, p0l); hhi0 = __hadd2(hhi0, p0h);
            hlo1 = __hadd2(hlo1, p1l); hhi1 = __hadd2(hhi1, p1h);
        }
        float2 fl0 = __half22float2(hlo0), fh0 = __half22float2(hhi0);
        float2 fl1 = __half22float2(hlo1), fh1 = __half22float2(hhi1);
        a00 += fl0.x; a01 += fl0.y; a02 += fh0.x; a03 += fh0.y;
        a10 += fl1.x; a11 += fl1.y; a12 += fh1.x; a13 += fh1.y;
        bs0 += 64; bs1 += 64;
    }
    // reduce over the 4 edge slots (lane bits 4,5)
    a00 += __shfl_xor(a00, 16); a01 += __shfl_xor(a01, 16);
    a02 += __shfl_xor(a02, 16); a03 += __shfl_xor(a03, 16);
    a10 += __shfl_xor(a10, 16); a11 += __shfl_xor(a11, 16);
    a12 += __shfl_xor(a12, 16); a13 += __shfl_xor(a13, 16);
    a00 += __shfl_xor(a00, 32); a01 += __shfl_xor(a01, 32);
    a02 += __shfl_xor(a02, 32); a03 += __shfl_xor(a03, 32);
    a10 += __shfl_xor(a10, 32); a11 += __shfl_xor(a11, 32);
    a12 += __shfl_xor(a12, 32); a13 += __shfl_xor(a13, 32);
    if (s == 0) {
        float di0 = dinv[node0];
        float di1 = dinv[node0 + 1];
        h2x2 self0 = xt4[(n0 << 4) + q];
        h2x2 self1 = xt4[((n0 + 1) << 4) + q];
        float2 s0l = __half22float2(self0.lo), s0h = __half22float2(self0.hi);
        float2 s1l = __half22float2(self1.lo), s1h = __half22float2(self1.hi);
        h2x2 out0, out1;
        out0.lo = __floats2half2_rn(di0 * (a00 + s0l.x), di0 * (a01 + s0l.y));
        out0.hi = __floats2half2_rn(di0 * (a02 + s0h.x), di0 * (a03 + s0h.y));
        out1.lo = __floats2half2_rn(di1 * (a10 + s1l.x), di1 * (a11 + s1l.y));
        out1.hi = __floats2half2_rn(di1 * (a12 + s1h.x), di1 * (a13 + s1h.y));
        ((h2x2*)vh)[(size_t)node0 * 16 + q] = out0;
        ((h2x2*)vh)[(size_t)(node0 + 1) * 16 + q] = out1;
    }
}

// K5: MFMA layer-1 GEMM (fp16 in, fp32 acc) + BN/ReLU + alpha-pool.
// alpha read as ONE float4 per tile (R7 shape; R9's inline-alpha regressed).
__global__ __launch_bounds__(256) void k_mfma_pool(
    const __half* __restrict__ vh, const float* __restrict__ alpha,
    const __half* __restrict__ W1t,
    const float* __restrict__ b1, const float* __restrict__ g1,
    const float* __restrict__ be1, const float* __restrict__ m1,
    const float* __restrict__ v1, float* __restrict__ pooled) {
    const int t = blockIdx.x & 7;
    const int bt = blockIdx.x >> 3;
    const int w = threadIdx.x >> 6, lane = threadIdx.x & 63;
    const int q = lane >> 4, col = lane & 15;
    const size_t tb = (size_t)t * N;

    f16x8 bfr[8][2];
    float sbv[8], stv[8];
#pragma unroll
    for (int jt = 0; jt < 8; jt++) {
        int j = jt * 16 + col;
        float s = g1[j] * rsqrtf(v1[j] + EPS);
        sbv[jt] = s;
        stv[jt] = s * b1[j] + be1[j] - m1[j] * s;
#pragma unroll
        for (int kk = 0; kk < 2; kk++)
            bfr[jt][kk] = *(const f16x8*)(W1t + (size_t)j * 64 + kk * 32 + q * 8);
    }
    float pool8[8];
#pragma unroll
    for (int jt = 0; jt < 8; jt++) pool8[jt] = 0.f;

    for (int i = 0; i < 8; i++) {
        int tau = bt * 32 + w * 8 + i;
        if (tau >= TILES_PT) break;
        int nb = tau * 16;
        const __half* vrow = vh + (tb + nb + col) * 64;
        f16x8 a0 = *(const f16x8*)(vrow + q * 8);
        f16x8 a1 = *(const f16x8*)(vrow + 32 + q * 8);
        float4 af = ((const float4*)(alpha + tb + nb))[q];
#pragma unroll
        for (int jt = 0; jt < 8; jt++) {
            f32x4 acc = {0.f, 0.f, 0.f, 0.f};
            acc = __builtin_amdgcn_mfma_f32_16x16x32_f16(a0, bfr[jt][0], acc, 0, 0, 0);
            acc = __builtin_amdgcn_mfma_f32_16x16x32_f16(a1, bfr[jt][1], acc, 0, 0, 0);
            float s = sbv[jt], sh = stv[jt];
            pool8[jt] += fmaxf(s * acc[0] + sh, 0.f) * af.x
                       + fmaxf(s * acc[1] + sh, 0.f) * af.y
                       + fmaxf(s * acc[2] + sh, 0.f) * af.z
                       + fmaxf(s * acc[3] + sh, 0.f) * af.w;
        }
    }
#pragma unroll
    for (int jt = 0; jt < 8; jt++) {
        pool8[jt] += __shfl_xor(pool8[jt], 16);
        pool8[jt] += __shfl_xor(pool8[jt], 32);
    }
    if (lane < 16) {
#pragma unroll
        for (int jt = 0; jt < 8; jt++)
            atomicAdd(&pooled[t * 128 + jt * 16 + lane], pool8[jt]);
    }
}

// K6: emb = bn2(pooled/N @ W2 + b2) + layer-0 x-part gates (8 parallel
// blocks, Wih0 STREAMED — no reg-cache, R17 spill trap). fp16 converts
// moved to k_partA tails (R13).
__global__ __launch_bounds__(512) void k_emb(
    const float* __restrict__ pooled,
    const float* __restrict__ W2, const float* __restrict__ b2,
    const float* __restrict__ g2, const float* __restrict__ be2,
    const float* __restrict__ m2, const float* __restrict__ v2,
    const float* __restrict__ Wih0, const float* __restrict__ bih0,
    const float* __restrict__ bhh0, float* __restrict__ gx0_g) {
    const int tid = threadIdx.x;
    const int t = blockIdx.x;
    __shared__ float pm[128];
    __shared__ float es[128];
    if (tid < 128) pm[tid] = pooled[t * 128 + tid] * (1.0f / N);
    __syncthreads();
    if (tid < 128) {
        float s = g2[tid] * rsqrtf(v2[tid] + EPS);
        float sh = be2[tid] - m2[tid] * s;
        float dot = 0.f;
#pragma unroll 8
        for (int k = 0; k < 128; k++) dot += pm[k] * W2[k * 128 + tid];
        es[tid] = s * (dot + b2[tid]) + sh;
    }
    __syncthreads();
    float dot = bih0[tid] + bhh0[tid];
    const float4* w = (const float4*)(Wih0 + tid * 128);
    const float4* e4 = (const float4*)es;
#pragma unroll
    for (int k4 = 0; k4 < 32; k4++) {
        float4 a = w[k4], bb = e4[k4];
        dot += a.x * bb.x + a.y * bb.y + a.z * bb.z + a.w * bb.w;
    }
    gx0_g[t * 512 + tid] = dot;
}

// K7: serial head — lstm0 -> gx1 -> lstm1 -> classifier, single block.
// Weights STREAMED each step (reg-cache spills at 1024 thr) in FP16:
// per-step traffic 128 KB instead of 256 KB (R3's fp32 stream measured at
// the per-CU L2-BW ceiling, so bytes are the lever). absmax 3e-5 (R9).
__global__ __launch_bounds__(1024) void k_head2(
    const float* __restrict__ gx0_g,
    const __half* __restrict__ Whh0h, const __half* __restrict__ Wih1h,
    const __half* __restrict__ Whh1h,
    const float* __restrict__ bih1, const float* __restrict__ bhh1,
    const float* __restrict__ Wc, const float* __restrict__ bc,
    float* __restrict__ out) {
    __shared__ float gx[T][512];               // gx0, later overwritten by gx1
    __shared__ float ys[T][128];
    __shared__ float h[128];
    __shared__ float part[1024];
    const int tid = threadIdx.x;
    const int r = tid & 511, hf = tid >> 9;
    float c = 0.f;
    for (int i = tid; i < T * 512; i += 1024) gx[i >> 9][i & 511] = gx0_g[i];
    if (tid < 128) h[tid] = 0.f;
    __syncthreads();
    // ---- LSTM layer 0 (Whh0 fp16-streamed) ----
    {
        const h2x2* wrow = (const h2x2*)(Whh0h + r * 128 + hf * 64);
        for (int t = 0; t < T; t++) {
            const float4* h4 = ((const float4*)h) + hf * 16;
            float dot = 0.f;
#pragma unroll
            for (int k = 0; k < 16; k++) {
                h2x2 wv = wrow[k];
                float4 hv = h4[k];
                float2 wl = __half22float2(wv.lo), wh = __half22float2(wv.hi);
                dot += wl.x * hv.x + wl.y * hv.y + wh.x * hv.z + wh.y * hv.w;
            }
            part[tid] = dot;
            __syncthreads();
            if (tid < 128) {
                float i_ = gx[t][tid]       + part[tid]       + part[512 + tid];
                float f_ = gx[t][128 + tid] + part[128 + tid] + part[640 + tid];
                float g_ = gx[t][256 + tid] + part[256 + tid] + part[768 + tid];
                float o_ = gx[t][384 + tid] + part[384 + tid] + part[896 + tid];
                c = sigm(f_) * c + sigm(i_) * tanhf(g_);
                float hv = sigm(o_) * tanhf(c);
                h[tid] = hv;
                ys[t][tid] = hv;
            }
            __syncthreads();
        }
    }
    // ---- gx1[t][r] = Wih1[r]·ys[t] + bias (fp16-streamed, overwrites gx) ----
    {
        const h2x2* wrow = (const h2x2*)(Wih1h + r * 128 + hf * 64);
        float bias = (hf == 0) ? (bih1[r] + bhh1[r]) : 0.f;
        for (int t = 0; t < T; t++) {
            const float4* y4 = ((const float4*)ys[t]) + hf * 16;
            float dot = bias;
#pragma unroll
            for (int k = 0; k < 16; k++) {
                h2x2 wv = wrow[k];
                float4 yv = y4[k];
                float2 wl = __half22float2(wv.lo), wh = __half22float2(wv.hi);
                dot += wl.x * yv.x + wl.y * yv.y + wh.x * yv.z + wh.y * yv.w;
            }
            part[tid] = dot;
            __syncthreads();
            if (tid < 512) gx[t][tid] = part[tid] + part[512 + tid];
            __syncthreads();
        }
    }
    // ---- LSTM layer 1 (Whh1 fp16-streamed) ----
    if (tid < 128) h[tid] = 0.f;
    c = 0.f;
    __syncthreads();
    {
        const h2x2* wrow = (const h2x2*)(Whh1h + r * 128 + hf * 64);
        for (int t = 0; t < T; t++) {
            const float4* h4 = ((const float4*)h) + hf * 16;
            float dot = 0.f;
#pragma unroll
            for (int k = 0; k < 16; k++) {
                h2x2 wv = wrow[k];
                float4 hv = h4[k];
                float2 wl = __half22float2(wv.lo), wh = __half22float2(wv.hi);
                dot += wl.x * hv.x + wl.y * hv.y + wh.x * hv.z + wh.y * hv.w;
            }
            part[tid] = dot;
            __syncthreads();
            if (tid < 128) {
                float i_ = gx[t][tid]       + part[tid]       + part[512 + tid];
                float f_ = gx[t][128 + tid] + part[128 + tid] + part[640 + tid];
                float g_ = gx[t][256 + tid] + part[256 + tid] + part[768 + tid];
                float o_ = gx[t][384 + tid] + part[384 + tid] + part[896 + tid];
                c = sigm(f_) * c + sigm(i_) * tanhf(g_);
                h[tid] = sigm(o_) * tanhf(c);
            }
            __syncthreads();
        }
    }
    if (tid < 2) {
        float dot = bc[tid];
#pragma unroll 8
        for (int k = 0; k < 128; k++) dot += h[k] * Wc[tid * 128 + k];
        out[tid] = dot;
    }
    if (tid < 128) out[2 + tid] = h[tid];
}

// ---------------------------------------------------------------------------
extern "C" void kernel_launch(void* const* d_in, const int* in_sizes, int n_in,
                              void* d_out, int out_size, void* d_ws, size_t ws_size,
                              hipStream_t stream) {
    const float* x    = (const float*)d_in[0];
    const int*   edges= (const int*)d_in[1];
    const float* W1   = (const float*)d_in[2];
    const float* b1   = (const float*)d_in[3];
    const float* g1   = (const float*)d_in[4];
    const float* be1  = (const float*)d_in[5];
    const float* m1   = (const float*)d_in[6];
    const float* v1   = (const float*)d_in[7];
    const float* W2   = (const float*)d_in[8];
    const float* b2   = (const float*)d_in[9];
    const float* g2   = (const float*)d_in[10];
    const float* be2  = (const float*)d_in[11];
    const float* m2   = (const float*)d_in[12];
    const float* v2   = (const float*)d_in[13];
    const float* Wih0 = (const float*)d_in[14];
    const float* Whh0 = (const float*)d_in[15];
    const float* bih0 = (const float*)d_in[16];
    const float* bhh0 = (const float*)d_in[17];
    const float* Wih1 = (const float*)d_in[18];
    const float* Whh1 = (const float*)d_in[19];
    const float* bih1 = (const float*)d_in[20];
    const float* bhh1 = (const float*)d_in[21];
    const float* Wc   = (const float*)d_in[22];
    const float* bc   = (const float*)d_in[23];

    char* base = (char*)d_ws;
    // Aliasing: hist_g dead after k_colsum; bpart written in k_partA, read by
    // k_pw (place+wsum), then dead; vh [0, 20.48 MB) written in k_gather.
    unsigned int* hist_g = (unsigned int*)base;                       // T*NBA*NPACK4 u32
    unsigned int* bpart  = (unsigned int*)(base + (size_t)T * NBA * NPACK * 4);
    __half*       vh     = (__half*)base;                             // T*N*64 f16
    char* p = base + (size_t)T * NBA * NPACK * 4 + (size_t)T * NBUK * CHUNKA * 4;
    __half* xh    = (__half*)p;             p += (size_t)T * N * 64 * 2 + 128; // + zero row
    int*   offs   = (int*)p;                p += (size_t)(T * N + 1) * 4 + 12; // keep 16B align
    int*   dega   = (int*)p;                p += (size_t)T * N * 4;
    float* dinv   = (float*)p;              p += (size_t)T * N * 4;
    float* alpha  = (float*)p;              p += (size_t)T * N * 4;
    __half* Whh0h = (__half*)p;             p += (size_t)65536 * 2;   // fp16 weights
    __half* Whh1h = (__half*)p;             p += (size_t)65536 * 2;
    __half* Wih1h = (__half*)p;             p += (size_t)65536 * 2;
    float* gx0_g  = (float*)p;              p += (size_t)T * 512 * 4;
    int*   eidx   = (int*)p;                p += (size_t)T * E * 4;   // 10.25 MB
    float* wpart  = (float*)p;              p += (size_t)T * NBUK * N * 4; // 20.5 MB
    int*   bcnt   = (int*)p;                p += (size_t)T * NBUK * NBUK * 4;
    float* pooled = (float*)p;              p += (size_t)T * 128 * 4;
    __half* W1t   = (__half*)p;

    k_partA<<<T * NBA + 48, 1024, 0, stream>>>(edges, hist_g, bpart, bcnt,
                                               Whh0, Whh1, Wih1, Whh0h, Whh1h, Wih1h);
    k_colsum<<<CSGRID + 32, 256, 0, stream>>>(hist_g, dega, dinv, W1, W1t, pooled);
    k_scanN<<<T, 1024, 0, stream>>>(dega, offs);
    k_pw<<<3 * T * NBUK + CVTBLK, 1024, 0, stream>>>(bpart, bcnt, offs, dinv,
                                                     eidx, wpart, x, xh);
    k_gather<<<GBLK2 + WREDBLK, 256, 0, stream>>>(eidx, offs, dinv, xh, wpart, alpha, vh);
    k_mfma_pool<<<8 * 40, 256, 0, stream>>>(vh, alpha, W1t, b1, g1, be1, m1, v1, pooled);
    k_emb<<<T, 512, 0, stream>>>(pooled, W2, b2, g2, be2, m2, v2, Wih0, bih0, bhh0, gx0_g);
    k_head2<<<1, 1024, 0, stream>>>(gx0_g, Whh0h, Wih1h, Whh1h,
                                    bih1, bhh1, Wc, bc, (float*)d_out);
}